// Round 1
// baseline (222.503 us; speedup 1.0000x reference)
//
#include <hip/hip_runtime.h>

// LaneAttention: per-lane MLP score -> per-group(8) softmax -> weighted pool of
// concat(ht, info, future) into out[32768, 192] fp32.
//
// Structure: 1024 blocks x 256 threads. Block b owns lanes [256b, 256b+256),
// i.e. 32 complete groups of 8 consecutive lanes (seg is sorted, 8 per id).
// No atomics / cross-block traffic needed.

#define LPG 8
#define GROUPS_PER_BLOCK 32

__global__ __launch_bounds__(256) void lane_attn_kernel(
    const float* __restrict__ ht,     // [M,64]
    const float* __restrict__ info,   // [M,64]
    const float* __restrict__ fut,    // [M,64]
    const float* __restrict__ W1,     // [128,16]
    const float* __restrict__ b1,     // [16]
    const float* __restrict__ W2,     // [16]
    const float* __restrict__ b2,     // [1]
    const int*   __restrict__ seg,    // [M]
    float*       __restrict__ out)    // [N_GROUPS,192]
{
    __shared__ float sprob[256];
    __shared__ int   sgid[GROUPS_PER_BLOCK];

    const int t         = threadIdx.x;
    const int blockBase = blockIdx.x * 256;
    const int lane      = blockBase + t;

    // ---------------- phase 1: per-lane MLP score ----------------
    // h[j] accumulators; W1/b1 indices are wave-uniform -> scalar loads (SGPR
    // operands on v_fma), no LDS staging needed for weights.
    float h[16];
#pragma unroll
    for (int j = 0; j < 16; ++j) h[j] = b1[j];

    const float4* htp = (const float4*)(ht   + (size_t)lane * 64);
    const float4* inp = (const float4*)(info + (size_t)lane * 64);

#pragma unroll 4
    for (int k4 = 0; k4 < 16; ++k4) {
        float4 v = htp[k4];
#pragma unroll
        for (int j = 0; j < 16; ++j) {
            h[j] = fmaf(v.x, W1[(k4 * 4 + 0) * 16 + j], h[j]);
            h[j] = fmaf(v.y, W1[(k4 * 4 + 1) * 16 + j], h[j]);
            h[j] = fmaf(v.z, W1[(k4 * 4 + 2) * 16 + j], h[j]);
            h[j] = fmaf(v.w, W1[(k4 * 4 + 3) * 16 + j], h[j]);
        }
    }
#pragma unroll 4
    for (int k4 = 0; k4 < 16; ++k4) {
        float4 v = inp[k4];
#pragma unroll
        for (int j = 0; j < 16; ++j) {
            h[j] = fmaf(v.x, W1[(64 + k4 * 4 + 0) * 16 + j], h[j]);
            h[j] = fmaf(v.y, W1[(64 + k4 * 4 + 1) * 16 + j], h[j]);
            h[j] = fmaf(v.z, W1[(64 + k4 * 4 + 2) * 16 + j], h[j]);
            h[j] = fmaf(v.w, W1[(64 + k4 * 4 + 3) * 16 + j], h[j]);
        }
    }

    float score = b2[0];
#pragma unroll
    for (int j = 0; j < 16; ++j)
        score = fmaf(fmaxf(h[j], 0.0f), W2[j], score);

    // ---------------- softmax within each 8-lane subgroup ----------------
    // wave=64 holds 8 complete groups; xor-shuffles 1/2/4 stay inside a group.
    float m = score;
    m = fmaxf(m, __shfl_xor(m, 1));
    m = fmaxf(m, __shfl_xor(m, 2));
    m = fmaxf(m, __shfl_xor(m, 4));
    float e = __expf(score - m);
    float s = e;
    s += __shfl_xor(s, 1);
    s += __shfl_xor(s, 2);
    s += __shfl_xor(s, 4);
    sprob[t] = e / s;

    if (t < GROUPS_PER_BLOCK) sgid[t] = seg[blockBase + t * LPG];
    __syncthreads();

    // ---------------- phase 2: softmax-weighted pooling ----------------
    // Wave w handles local groups [8w, 8w+8). Thread c covers output columns
    // {c, 64+c, 128+c}. Row reads are coalesced 256B; ht/info are L2-hot from
    // phase 1, fut is first-touch.
    const int wave = t >> 6;
    const int c    = t & 63;
    for (int gg = 0; gg < 8; ++gg) {
        const int gl  = wave * 8 + gg;
        const int gid = sgid[gl];
        const int r0  = blockBase + gl * LPG;
        float a0 = 0.0f, a1 = 0.0f, a2 = 0.0f;
#pragma unroll
        for (int i = 0; i < LPG; ++i) {
            const float  p = sprob[gl * LPG + i];
            const size_t r = (size_t)(r0 + i) * 64;
            a0 = fmaf(p, ht[r + c],   a0);
            a1 = fmaf(p, info[r + c], a1);
            a2 = fmaf(p, fut[r + c],  a2);
        }
        float* o = out + (size_t)gid * 192;
        o[c]       = a0;
        o[64 + c]  = a1;
        o[128 + c] = a2;
    }
}

extern "C" void kernel_launch(void* const* d_in, const int* in_sizes, int n_in,
                              void* d_out, int out_size, void* d_ws, size_t ws_size,
                              hipStream_t stream) {
    const float* ht   = (const float*)d_in[0];
    const float* info = (const float*)d_in[1];
    const float* fut  = (const float*)d_in[2];
    const float* W1   = (const float*)d_in[3];
    const float* b1   = (const float*)d_in[4];
    const float* W2   = (const float*)d_in[5];
    const float* b2   = (const float*)d_in[6];
    const int*   seg  = (const int*)d_in[7];
    float*       out  = (float*)d_out;

    const int M = in_sizes[7];           // 262144 lanes
    const int blocks = M / 256;          // 1024

    lane_attn_kernel<<<blocks, 256, 0, stream>>>(ht, info, fut, W1, b1, W2, b2,
                                                 seg, out);
}